// Round 1
// baseline (308.829 us; speedup 1.0000x reference)
//
#include <hip/hip_runtime.h>
#include <hip/hip_bf16.h>

#define B_DIM 4096
#define K_TOT 2048   // IN + H
#define N_TOT 4096   // 4*H
#define H_DIM 1024

typedef short bf16x8 __attribute__((ext_vector_type(8)));
typedef float f32x4 __attribute__((ext_vector_type(4)));
typedef unsigned short u16x8 __attribute__((ext_vector_type(8)));

typedef __attribute__((address_space(1))) const unsigned gas_u32;
typedef __attribute__((address_space(3))) unsigned las_u32;

static __device__ __forceinline__ unsigned short f2bf(float f) {
  union { float f; unsigned u; } v; v.f = f;
  unsigned r = v.u + 0x7FFF + ((v.u >> 16) & 1);  // RNE
  return (unsigned short)(r >> 16);
}

// ---------------- pack A = [x | h] as bf16 (B x 2048) ----------------
__global__ void pack_a(const float* __restrict__ x, const float* __restrict__ hp,
                       u16x8* __restrict__ A) {
  int t = blockIdx.x * blockDim.x + threadIdx.x;
  int idx = t << 3;                 // element index, 8 per thread
  int b = idx >> 11;
  int k = idx & 2047;
  const float* src = (k < 1024) ? (x + b * 1024 + k) : (hp + b * 1024 + (k - 1024));
  float4 lo = *(const float4*)src;
  float4 hi = *(const float4*)(src + 4);
  u16x8 v;
  v[0] = f2bf(lo.x); v[1] = f2bf(lo.y); v[2] = f2bf(lo.z); v[3] = f2bf(lo.w);
  v[4] = f2bf(hi.x); v[5] = f2bf(hi.y); v[6] = f2bf(hi.z); v[7] = f2bf(hi.w);
  A[t] = v;
}

// ------------- pack W = [Wx | Wh] as bf16, rows in gate order (4096 x 2048) -------------
__global__ void pack_w(const float* __restrict__ W0, const float* __restrict__ W1,
                       const float* __restrict__ W2, const float* __restrict__ W3,
                       const float* __restrict__ W4, const float* __restrict__ W5,
                       const float* __restrict__ W6, const float* __restrict__ W7,
                       u16x8* __restrict__ Wc) {
  int t = blockIdx.x * blockDim.x + threadIdx.x;
  int idx = t << 3;
  int n = idx >> 11;                // output row (gate*1024 + j)
  int k = idx & 2047;
  int gate = n >> 10;
  int j = n & 1023;
  int s = (k < 1024) ? gate : gate + 4;   // 0..3 -> Wx gates, 4..7 -> Wh gates
  const float* base =
      (s == 0) ? W0 : (s == 1) ? W1 : (s == 2) ? W2 : (s == 3) ? W3 :
      (s == 4) ? W4 : (s == 5) ? W5 : (s == 6) ? W6 : W7;
  const float* src = base + j * 1024 + (k & 1023);
  float4 lo = *(const float4*)src;
  float4 hi = *(const float4*)(src + 4);
  u16x8 v;
  v[0] = f2bf(lo.x); v[1] = f2bf(lo.y); v[2] = f2bf(lo.z); v[3] = f2bf(lo.w);
  v[4] = f2bf(hi.x); v[5] = f2bf(hi.y); v[6] = f2bf(hi.z); v[7] = f2bf(hi.w);
  Wc[t] = v;
}

// ------------- GEMM: gates(B x 4096 fp32) = A(B x 2048) @ W(4096 x 2048)^T -------------
// m97 structure: 128x128 tile, 4 waves of 64x64, 16x16x32 bf16 MFMA,
// global_load_lds width=16 staging, ds_read_b128 fragments.
__global__ __launch_bounds__(256) void gemm_gates(
    const unsigned short* __restrict__ A,
    const unsigned short* __restrict__ W,
    float* __restrict__ G) {
  __shared__ unsigned short As[128 * 32];
  __shared__ unsigned short Bs[128 * 32];
  const int tid = threadIdx.x;
  const int wave = tid >> 6;
  const int lane = tid & 63;
  const int m0 = blockIdx.y << 7;
  const int n0 = blockIdx.x << 7;
  const int wm = (wave >> 1) << 6;  // wave quadrant rows
  const int wn = (wave & 1) << 6;   // wave quadrant cols

  f32x4 acc[4][4];
#pragma unroll
  for (int mi = 0; mi < 4; ++mi)
#pragma unroll
    for (int ni = 0; ni < 4; ++ni)
      acc[mi][ni] = (f32x4){0.f, 0.f, 0.f, 0.f};

  // Staging coords: chunk = wave*2 + it; 1024B (16 rows) per chunk,
  // lane l lands at chunk_base + l*16 (global_load_lds wave-uniform dest rule).
  const int c0 = wave * 2;
  const int srow = c0 * 16 + (lane >> 2);
  const int scol = (lane & 3) * 8;
  const unsigned short* aptr0 = A + (long)(m0 + srow) * K_TOT + scol;
  const unsigned short* aptr1 = A + (long)(m0 + srow + 16) * K_TOT + scol;
  const unsigned short* bptr0 = W + (long)(n0 + srow) * K_TOT + scol;
  const unsigned short* bptr1 = W + (long)(n0 + srow + 16) * K_TOT + scol;
  char* lA0 = (char*)As + c0 * 1024;
  char* lA1 = lA0 + 1024;
  char* lB0 = (char*)Bs + c0 * 1024;
  char* lB1 = lB0 + 1024;

  const int fr = lane & 15;            // fragment row/col within 16-tile
  const int fko = (lane >> 4) * 16;    // byte offset along k

  for (int k0 = 0; k0 < K_TOT; k0 += 32) {
    __builtin_amdgcn_global_load_lds((gas_u32*)(aptr0 + k0), (las_u32*)lA0, 16, 0, 0);
    __builtin_amdgcn_global_load_lds((gas_u32*)(aptr1 + k0), (las_u32*)lA1, 16, 0, 0);
    __builtin_amdgcn_global_load_lds((gas_u32*)(bptr0 + k0), (las_u32*)lB0, 16, 0, 0);
    __builtin_amdgcn_global_load_lds((gas_u32*)(bptr1 + k0), (las_u32*)lB1, 16, 0, 0);
    __syncthreads();
    bf16x8 af[4], bfv[4];
#pragma unroll
    for (int i = 0; i < 4; ++i) {
      af[i]  = *(const bf16x8*)((const char*)As + (wm + i * 16 + fr) * 64 + fko);
      bfv[i] = *(const bf16x8*)((const char*)Bs + (wn + i * 16 + fr) * 64 + fko);
    }
#pragma unroll
    for (int mi = 0; mi < 4; ++mi)
#pragma unroll
      for (int ni = 0; ni < 4; ++ni)
        acc[mi][ni] = __builtin_amdgcn_mfma_f32_16x16x32_bf16(af[mi], bfv[ni], acc[mi][ni], 0, 0, 0);
    __syncthreads();
  }

  // Epilogue: C/D layout col=lane&15, row=(lane>>4)*4+reg  [m89/m91 verified]
  const int ccol = lane & 15;
  const int crow = (lane >> 4) * 4;
#pragma unroll
  for (int mi = 0; mi < 4; ++mi) {
#pragma unroll
    for (int ni = 0; ni < 4; ++ni) {
      float* gp = G + (long)(m0 + wm + mi * 16 + crow) * N_TOT + (n0 + wn + ni * 16 + ccol);
      gp[0]                 = acc[mi][ni][0];
      gp[N_TOT]             = acc[mi][ni][1];
      gp[2 * (long)N_TOT]   = acc[mi][ni][2];
      gp[3 * (long)N_TOT]   = acc[mi][ni][3];
    }
  }
}

// ------------- pointwise LSTM epilogue -------------
static __device__ __forceinline__ float sigm(float x) {
  return 1.0f / (1.0f + __expf(-x));
}
static __device__ __forceinline__ float tanh_fast(float x) {
  x = fminf(fmaxf(x, -15.f), 15.f);
  float t = __expf(-2.0f * x);
  return (1.0f - t) / (1.0f + t);
}

__global__ void lstm_pointwise(const float* __restrict__ G, const float* __restrict__ cp,
                               const float* __restrict__ bii, const float* __restrict__ bif,
                               const float* __restrict__ big, const float* __restrict__ bio,
                               float* __restrict__ out) {
  int t = blockIdx.x * blockDim.x + threadIdx.x;
  int idx = t << 2;               // 4 elems/thread over B*H
  int b = idx >> 10;
  int j = idx & 1023;
  const float* gr = G + (long)b * N_TOT;
  float4 zi = *(const float4*)(gr + j);
  float4 zf = *(const float4*)(gr + 1024 + j);
  float4 zg = *(const float4*)(gr + 2048 + j);
  float4 zo = *(const float4*)(gr + 3072 + j);
  float4 vbi = *(const float4*)(bii + j);
  float4 vbf = *(const float4*)(bif + j);
  float4 vbg = *(const float4*)(big + j);
  float4 vbo = *(const float4*)(bio + j);
  float4 vc = *(const float4*)(cp + idx);

  const float* zia = (const float*)&zi; const float* zfa = (const float*)&zf;
  const float* zga = (const float*)&zg; const float* zoa = (const float*)&zo;
  const float* bia = (const float*)&vbi; const float* bfa = (const float*)&vbf;
  const float* bga = (const float*)&vbg; const float* boa = (const float*)&vbo;
  const float* vca = (const float*)&vc;

  float4 vh, vct, vi, vf, vg, vo;
  float* vha = (float*)&vh; float* vcta = (float*)&vct;
  float* via = (float*)&vi; float* vfa = (float*)&vf;
  float* vga = (float*)&vg; float* voa = (float*)&vo;
#pragma unroll
  for (int q = 0; q < 4; ++q) {
    float iv = sigm(zia[q] + bia[q]);
    float fv = sigm(zfa[q] + bfa[q]);
    float gv = tanh_fast(zga[q] + bga[q]);
    float ov = sigm(zoa[q] + boa[q]);
    float cv = fv * vca[q] + iv * gv;
    float hv = ov * tanh_fast(cv);
    via[q] = iv; vfa[q] = fv; vga[q] = gv; voa[q] = ov; vcta[q] = cv; vha[q] = hv;
  }
  const long BH = (long)B_DIM * H_DIM;
  *(float4*)(out + idx) = vh;
  *(float4*)(out + BH + idx) = vct;
  *(float4*)(out + 2 * BH + idx) = vi;
  *(float4*)(out + 3 * BH + idx) = vf;
  *(float4*)(out + 4 * BH + idx) = vg;
  *(float4*)(out + 5 * BH + idx) = vo;
}

extern "C" void kernel_launch(void* const* d_in, const int* in_sizes, int n_in,
                              void* d_out, int out_size, void* d_ws, size_t ws_size,
                              hipStream_t stream) {
  const float* x    = (const float*)d_in[0];
  const float* h    = (const float*)d_in[1];
  const float* c    = (const float*)d_in[2];
  const float* W_ii = (const float*)d_in[3];
  const float* b_ii = (const float*)d_in[4];
  const float* W_if = (const float*)d_in[5];
  const float* b_if = (const float*)d_in[6];
  const float* W_ig = (const float*)d_in[7];
  const float* b_ig = (const float*)d_in[8];
  const float* W_io = (const float*)d_in[9];
  const float* b_io = (const float*)d_in[10];
  const float* W_hi = (const float*)d_in[11];
  const float* W_hf = (const float*)d_in[12];
  const float* W_hg = (const float*)d_in[13];
  const float* W_ho = (const float*)d_in[14];

  // workspace layout: A_cat bf16 16MB | W_cat bf16 16MB | gates fp32 64MB
  unsigned short* Abf = (unsigned short*)d_ws;
  unsigned short* Wbf = (unsigned short*)((char*)d_ws + (size_t)16 * 1024 * 1024);
  float* G = (float*)((char*)d_ws + (size_t)32 * 1024 * 1024);

  // B*K_TOT/8 threads = 1M -> 4096 blocks
  pack_a<<<4096, 256, 0, stream>>>(x, h, (u16x8*)Abf);
  pack_w<<<4096, 256, 0, stream>>>(W_ii, W_if, W_ig, W_io, W_hi, W_hf, W_hg, W_ho,
                                   (u16x8*)Wbf);
  dim3 grid(N_TOT / 128, B_DIM / 128);
  gemm_gates<<<grid, 256, 0, stream>>>(Abf, Wbf, G);
  // B*H/4 threads = 1M -> 4096 blocks
  lstm_pointwise<<<4096, 256, 0, stream>>>(G, c, b_ii, b_if, b_ig, b_io, (float*)d_out);
}

// Round 2
// 282.488 us; speedup vs baseline: 1.0932x; 1.0932x over previous
//
#include <hip/hip_runtime.h>
#include <hip/hip_bf16.h>

#define B_DIM 4096
#define K_TOT 2048   // IN + H
#define H_DIM 1024

typedef short bf16x8 __attribute__((ext_vector_type(8)));
typedef float f32x4 __attribute__((ext_vector_type(4)));
typedef unsigned short u16x8 __attribute__((ext_vector_type(8)));

typedef __attribute__((address_space(1))) const unsigned gas_u32;
typedef __attribute__((address_space(3))) unsigned las_u32;

static __device__ __forceinline__ unsigned short f2bf(float f) {
  union { float f; unsigned u; } v; v.f = f;
  unsigned r = v.u + 0x7FFF + ((v.u >> 16) & 1);  // RNE
  return (unsigned short)(r >> 16);
}

// ---------------- pack A = [x | h] as bf16 (B x 2048) ----------------
__global__ void pack_a(const float* __restrict__ x, const float* __restrict__ hp,
                       u16x8* __restrict__ A) {
  int t = blockIdx.x * blockDim.x + threadIdx.x;
  int idx = t << 3;                 // element index, 8 per thread
  int b = idx >> 11;
  int k = idx & 2047;
  const float* src = (k < 1024) ? (x + b * 1024 + k) : (hp + b * 1024 + (k - 1024));
  float4 lo = *(const float4*)src;
  float4 hi = *(const float4*)(src + 4);
  u16x8 v;
  v[0] = f2bf(lo.x); v[1] = f2bf(lo.y); v[2] = f2bf(lo.z); v[3] = f2bf(lo.w);
  v[4] = f2bf(hi.x); v[5] = f2bf(hi.y); v[6] = f2bf(hi.z); v[7] = f2bf(hi.w);
  A[t] = v;
}

// ------------- pack W = [Wx | Wh] as bf16, rows in gate order (4096 x 2048) -------------
__global__ void pack_w(const float* __restrict__ W0, const float* __restrict__ W1,
                       const float* __restrict__ W2, const float* __restrict__ W3,
                       const float* __restrict__ W4, const float* __restrict__ W5,
                       const float* __restrict__ W6, const float* __restrict__ W7,
                       u16x8* __restrict__ Wc) {
  int t = blockIdx.x * blockDim.x + threadIdx.x;
  int idx = t << 3;
  int n = idx >> 11;                // output row (gate*1024 + j)
  int k = idx & 2047;
  int gate = n >> 10;
  int j = n & 1023;
  int s = (k < 1024) ? gate : gate + 4;   // 0..3 -> Wx gates, 4..7 -> Wh gates
  const float* base =
      (s == 0) ? W0 : (s == 1) ? W1 : (s == 2) ? W2 : (s == 3) ? W3 :
      (s == 4) ? W4 : (s == 5) ? W5 : (s == 6) ? W6 : W7;
  const float* src = base + j * 1024 + (k & 1023);
  float4 lo = *(const float4*)src;
  float4 hi = *(const float4*)(src + 4);
  u16x8 v;
  v[0] = f2bf(lo.x); v[1] = f2bf(lo.y); v[2] = f2bf(lo.z); v[3] = f2bf(lo.w);
  v[4] = f2bf(hi.x); v[5] = f2bf(hi.y); v[6] = f2bf(hi.z); v[7] = f2bf(hi.w);
  Wc[t] = v;
}

// ------------- fused GEMM + LSTM epilogue -------------
// Block: 128 rows x (4 gates x 32 j-cols). Wave: 64 rows x (4 gates x 16 j).
// acc[mi][gate] -> each lane holds z_i,z_f,z_g,z_o for the SAME (row,j) across
// the gate index, so the LSTM pointwise is in-register.
// LDS slot swizzle: 16B slot s at row r holds global k-group g = s ^ ((r>>1)&3)
// -> ds_read_b128 conflicts drop from 8-way to 2-way (free).
static __device__ __forceinline__ float sigm(float x) {
  return 1.0f / (1.0f + __expf(-x));
}
static __device__ __forceinline__ float tanh_fast(float x) {
  x = fminf(fmaxf(x, -15.f), 15.f);
  float t = __expf(-2.0f * x);
  return (1.0f - t) / (1.0f + t);
}

__global__ __launch_bounds__(256) void gemm_lstm(
    const unsigned short* __restrict__ A,   // B x 2048 bf16
    const unsigned short* __restrict__ W,   // 4096 x 2048 bf16, gate-major rows
    const float* __restrict__ cp,
    const float* __restrict__ bii, const float* __restrict__ bif,
    const float* __restrict__ big, const float* __restrict__ bio,
    float* __restrict__ out) {
  __shared__ unsigned short As[128 * 32];
  __shared__ unsigned short Bs[128 * 32];
  const int tid = threadIdx.x;
  const int wave = tid >> 6;
  const int lane = tid & 63;
  const int m0 = blockIdx.y << 7;       // 128-row strip
  const int j0 = blockIdx.x << 5;       // 32-wide j strip
  const int wm = (wave >> 1) << 6;      // wave row half (64)
  const int wj16 = (wave & 1) << 4;     // wave j half (16)

  f32x4 acc[4][4];
#pragma unroll
  for (int mi = 0; mi < 4; ++mi)
#pragma unroll
    for (int ni = 0; ni < 4; ++ni)
      acc[mi][ni] = (f32x4){0.f, 0.f, 0.f, 0.f};

  // ---- staging: wave stages chunks c0,c0+1 for A and B (16 rows x 64B each)
  const int c0 = wave * 2;
  const int lr = lane >> 2;                       // row within chunk
  const int ls = lane & 3;                        // LDS 16B slot
  const int g  = ls ^ ((lr >> 1) & 3);            // swizzled global k-group
  // A rows: m0 + c*16 + lr
  const unsigned short* aptr0 = A + (long)(m0 + c0 * 16 + lr) * K_TOT + g * 8;
  const unsigned short* aptr1 = A + (long)(m0 + (c0 + 1) * 16 + lr) * K_TOT + g * 8;
  // B rows: LDS row rr -> W row (rr>>5)*1024 + j0 + (rr&31)
  const int rr0 = c0 * 16 + lr;
  const int rr1 = rr0 + 16;
  const unsigned short* bptr0 =
      W + (long)((rr0 >> 5) * 1024 + j0 + (rr0 & 31)) * K_TOT + g * 8;
  const unsigned short* bptr1 =
      W + (long)((rr1 >> 5) * 1024 + j0 + (rr1 & 31)) * K_TOT + g * 8;
  char* lA0 = (char*)As + c0 * 1024;
  char* lA1 = lA0 + 1024;
  char* lB0 = (char*)Bs + c0 * 1024;
  char* lB1 = lB0 + 1024;

  const int fr = lane & 15;                       // fragment row within 16-tile
  const int gg = lane >> 4;                       // k-group 0..3
  const int sl = (gg ^ ((fr >> 1) & 3)) * 16;     // swizzled slot byte offset

  for (int k0 = 0; k0 < K_TOT; k0 += 32) {
    __builtin_amdgcn_global_load_lds((gas_u32*)(aptr0 + k0), (las_u32*)lA0, 16, 0, 0);
    __builtin_amdgcn_global_load_lds((gas_u32*)(aptr1 + k0), (las_u32*)lA1, 16, 0, 0);
    __builtin_amdgcn_global_load_lds((gas_u32*)(bptr0 + k0), (las_u32*)lB0, 16, 0, 0);
    __builtin_amdgcn_global_load_lds((gas_u32*)(bptr1 + k0), (las_u32*)lB1, 16, 0, 0);
    __syncthreads();
    bf16x8 af[4], bfv[4];
#pragma unroll
    for (int i = 0; i < 4; ++i) {
      af[i]  = *(const bf16x8*)((const char*)As + (wm + i * 16 + fr) * 64 + sl);
      bfv[i] = *(const bf16x8*)((const char*)Bs + (i * 32 + wj16 + fr) * 64 + sl);
    }
#pragma unroll
    for (int mi = 0; mi < 4; ++mi)
#pragma unroll
      for (int ni = 0; ni < 4; ++ni)
        acc[mi][ni] = __builtin_amdgcn_mfma_f32_16x16x32_bf16(af[mi], bfv[ni], acc[mi][ni], 0, 0, 0);
    __syncthreads();
  }

  // ---- fused LSTM epilogue
  // C/D layout: col=lane&15, row=(lane>>4)*4+reg  [m89/m91 verified]
  const int ccol = lane & 15;
  const int crow = (lane >> 4) * 4;
  const int j = j0 + wj16 + ccol;
  const float bi = bii[j];
  const float bff = bif[j];
  const float bg = big[j];
  const float bo = bio[j];
  const long BH = (long)B_DIM * H_DIM;
#pragma unroll
  for (int mi = 0; mi < 4; ++mi) {
#pragma unroll
    for (int reg = 0; reg < 4; ++reg) {
      const int row = m0 + wm + mi * 16 + crow + reg;
      const long p = (long)row * H_DIM + j;
      const float cvp = cp[p];
      const float iv = sigm(acc[mi][0][reg] + bi);
      const float fv = sigm(acc[mi][1][reg] + bff);
      const float gv = tanh_fast(acc[mi][2][reg] + bg);
      const float ov = sigm(acc[mi][3][reg] + bo);
      const float cv = fv * cvp + iv * gv;
      const float hv = ov * tanh_fast(cv);
      out[p]          = hv;
      out[BH + p]     = cv;
      out[2 * BH + p] = iv;
      out[3 * BH + p] = fv;
      out[4 * BH + p] = gv;
      out[5 * BH + p] = ov;
    }
  }
}

extern "C" void kernel_launch(void* const* d_in, const int* in_sizes, int n_in,
                              void* d_out, int out_size, void* d_ws, size_t ws_size,
                              hipStream_t stream) {
  const float* x    = (const float*)d_in[0];
  const float* h    = (const float*)d_in[1];
  const float* c    = (const float*)d_in[2];
  const float* W_ii = (const float*)d_in[3];
  const float* b_ii = (const float*)d_in[4];
  const float* W_if = (const float*)d_in[5];
  const float* b_if = (const float*)d_in[6];
  const float* W_ig = (const float*)d_in[7];
  const float* b_ig = (const float*)d_in[8];
  const float* W_io = (const float*)d_in[9];
  const float* b_io = (const float*)d_in[10];
  const float* W_hi = (const float*)d_in[11];
  const float* W_hf = (const float*)d_in[12];
  const float* W_hg = (const float*)d_in[13];
  const float* W_ho = (const float*)d_in[14];

  // workspace: A_cat bf16 16MB | W_cat bf16 16MB
  unsigned short* Abf = (unsigned short*)d_ws;
  unsigned short* Wbf = (unsigned short*)((char*)d_ws + (size_t)16 * 1024 * 1024);

  pack_a<<<4096, 256, 0, stream>>>(x, h, (u16x8*)Abf);
  pack_w<<<4096, 256, 0, stream>>>(W_ii, W_if, W_ig, W_io, W_hi, W_hf, W_hg, W_ho,
                                   (u16x8*)Wbf);
  dim3 grid(H_DIM / 32, B_DIM / 128);   // 32 x 32 blocks
  gemm_lstm<<<grid, 256, 0, stream>>>(Abf, Wbf, c, b_ii, b_if, b_ig, b_io,
                                      (float*)d_out);
}